// Round 2
// baseline (600.664 us; speedup 1.0000x reference)
//
#include <hip/hip_runtime.h>
#include <hip/hip_bf16.h>

// ---------------------------------------------------------------------------
// Fully fused: x=(x_c+x_t) -> QKV (bf16 MFMA) -> per-token 8x8 cross-head
// attention -> Wo projection -> fp32 NCHW out. One main kernel, T=32 tokens
// per block, 2 blocks/CU (66 KB LDS), conflict-engineered LDS strides.
// Head inner/outer permutation folded into permuted Wq/Wk/Wv rows (prep).
// ---------------------------------------------------------------------------

typedef unsigned short u16;
typedef __bf16 bf16x8 __attribute__((ext_vector_type(8)));
typedef float f32x4 __attribute__((ext_vector_type(4)));
typedef unsigned short u16x8 __attribute__((ext_vector_type(8)));
typedef unsigned short u16x4 __attribute__((ext_vector_type(4)));

constexpr int CH = 256;        // channels
constexpr int HWN = 16384;     // H*W
constexpr int T = 32;          // tokens per block
// LDS strides (elems). quad-step s = stride/8 mod 32 chosen per access pattern:
constexpr int LDXe = 272;      // X^T: s=34==2 -> staging writes & B-frag reads 2-way (free)
constexpr int LDOe = 280;      // O:   s=35==3 -> attn O-writes & Wo B-frag reads <=2-way
constexpr int LQe  = 776;      // QKV: s=97==1 -> attn q reads free, k/v broadcast free

// ws byte layout
constexpr size_t WS_WQKV = 0;             // 768*256 u16
constexpr size_t WS_WO   = 393216;        // 256*256 u16
constexpr size_t WS_BIAS = 524288;        // 768 f32

__device__ __forceinline__ u16 f2bf(float f) {
    unsigned u = __builtin_bit_cast(unsigned, f);
    unsigned r = u + 0x7FFFu + ((u >> 16) & 1u);   // RNE
    return (u16)(r >> 16);
}
__device__ __forceinline__ float bf2f(u16 u) {
    return __builtin_bit_cast(float, (unsigned)u << 16);
}

// --- prep: permuted bf16 weights + permuted biases -------------------------
// row j of Wq' = row (j%32)*8 + j/32 of Wq  (head-inner -> head-outer fold)
__global__ void prep_kernel(const float* __restrict__ Wq, const float* __restrict__ Wk,
                            const float* __restrict__ Wv, const float* __restrict__ Wo,
                            const float* __restrict__ bq, const float* __restrict__ bk,
                            const float* __restrict__ bv,
                            u16* __restrict__ Wqkv_b, u16* __restrict__ Wo_b,
                            float* __restrict__ bias_qkv) {
    const int i = blockIdx.x;    // 0..767
    const int c = threadIdx.x;   // 0..255
    const int j = i & 255;
    const int p = ((j & 31) << 3) + (j >> 5);
    const float* Wsrc = (i < 256) ? Wq : (i < 512 ? Wk : Wv);
    const float* bsrc = (i < 256) ? bq : (i < 512 ? bk : bv);
    Wqkv_b[i * 256 + c] = f2bf(Wsrc[p * 256 + c]);
    if (i < 256) Wo_b[i * 256 + c] = f2bf(Wo[i * 256 + c]);
    if (c == 0) bias_qkv[i] = bsrc[p];
}

// --- fused main kernel -----------------------------------------------------
__launch_bounds__(512, 4)
__global__ void fused_kernel(const float* __restrict__ x_c, const float* __restrict__ x_t,
                             const u16* __restrict__ Wqkv_b, const u16* __restrict__ Wo_b,
                             const float* __restrict__ bias_qkv, const float* __restrict__ bo,
                             float* __restrict__ out) {
    __shared__ u16 XO[T * LDOe];     // X^T tile (stride LDXe), later O tile (stride LDOe)
    __shared__ u16 QKVT[T * LQe];    // [t][q 0..255 | k 256..511 | v 512..767]

    const int tid = threadIdx.x;
    const int lane = tid & 63;
    const int wave = tid >> 6;       // 0..7
    const int tok0 = blockIdx.x * T;
    const int b = tok0 >> 14;
    const int hw0 = tok0 & (HWN - 1);
    const float* __restrict__ xc = x_c + (size_t)b * CH * HWN + hw0;
    const float* __restrict__ xt = x_t + (size_t)b * CH * HWN + hw0;

    // ---- phase 0: stage X^T (fused add + bf16). float2 along tokens,
    //      one b128 LDS write per 8 channels. writes 2-way (free).
    {
        const int t2 = (tid & 15) * 2;       // token pair
        const int c0 = (tid >> 4) * 8;       // 8-channel group, 0..248
        float2 va[8], vb[8];
#pragma unroll
        for (int j = 0; j < 8; ++j) {
            const size_t off = (size_t)(c0 + j) * HWN + t2;
            va[j] = *(const float2*)&xc[off];
            vb[j] = *(const float2*)&xt[off];
        }
        u16x8 r0, r1;
#pragma unroll
        for (int j = 0; j < 8; ++j) {
            r0[j] = f2bf(va[j].x + vb[j].x);
            r1[j] = f2bf(va[j].y + vb[j].y);
        }
        *(u16x8*)&XO[t2 * LDXe + c0] = r0;
        *(u16x8*)&XO[(t2 + 1) * LDXe + c0] = r1;
    }
    __syncthreads();

    // ---- phase 1: QKV' = Wqkv' @ X  (M=768, N=32, K=256), 16x16x32 bf16.
    //      wave owns 96 rows (6 m-tiles) x 2 col-tiles. B-frag reads free.
    {
        const int l15 = lane & 15;
        const int l4 = lane >> 4;
        const int m_base = wave * 96;
        f32x4 acc[6][2];
#pragma unroll
        for (int i = 0; i < 6; ++i)
#pragma unroll
            for (int j = 0; j < 2; ++j) acc[i][j] = (f32x4){0.f, 0.f, 0.f, 0.f};

#pragma unroll
        for (int kk = 0; kk < 8; ++kk) {
            const int koff = kk * 32 + l4 * 8;
            bf16x8 bfr[2];
#pragma unroll
            for (int ct = 0; ct < 2; ++ct)
                bfr[ct] = __builtin_bit_cast(bf16x8,
                    *(const u16x8*)&XO[(ct * 16 + l15) * LDXe + koff]);
#pragma unroll
            for (int mt = 0; mt < 6; ++mt) {
                const bf16x8 afr = __builtin_bit_cast(bf16x8,
                    *(const u16x8*)&Wqkv_b[(m_base + mt * 16 + l15) * 256 + koff]);
#pragma unroll
                for (int ct = 0; ct < 2; ++ct)
                    acc[mt][ct] = __builtin_amdgcn_mfma_f32_16x16x32_bf16(
                        afr, bfr[ct], acc[mt][ct], 0, 0, 0);
            }
        }
        // epilogue: +bias, pack 4 consecutive channels -> one 8B LDS write
#pragma unroll
        for (int mt = 0; mt < 6; ++mt) {
            const int i0 = m_base + mt * 16 + l4 * 4;
            const f32x4 bias = *(const f32x4*)&bias_qkv[i0];
#pragma unroll
            for (int ct = 0; ct < 2; ++ct) {
                const int t = ct * 16 + l15;
                u16x4 pk;
#pragma unroll
                for (int r = 0; r < 4; ++r) pk[r] = f2bf(acc[mt][ct][r] + bias[r]);
                *(u16x4*)&QKVT[t * LQe + i0] = pk;
            }
        }
    }
    __syncthreads();

    // ---- phase 2: per-token 8x8 cross-head attention (256 threads).
    //      q reads free (t+4h quads), k/v reads broadcast across a token's
    //      8 threads. O written to XO (stride LDOe), <=2-way.
    if (tid < T * 8) {
        const int t = tid >> 3;      // 0..31
        const int h = tid & 7;       // head
        const u16* __restrict__ row = &QKVT[t * LQe];
        float q[32];
#pragma unroll
        for (int i = 0; i < 4; ++i) {
            const u16x8 v = *(const u16x8*)&row[h * 32 + i * 8];
#pragma unroll
            for (int e = 0; e < 8; ++e) q[i * 8 + e] = bf2f(v[e]);
        }
        float dot[8];
#pragma unroll
        for (int g = 0; g < 8; ++g) {
            float s = 0.f;
#pragma unroll
            for (int i = 0; i < 4; ++i) {
                const u16x8 v = *(const u16x8*)&row[256 + g * 32 + i * 8];
#pragma unroll
                for (int e = 0; e < 8; ++e) s += q[i * 8 + e] * bf2f(v[e]);
            }
            dot[g] = s * 0.17677669529663687f;   // 32^-0.5
        }
        float m = dot[0];
#pragma unroll
        for (int g = 1; g < 8; ++g) m = fmaxf(m, dot[g]);
        float ssum = 0.f;
#pragma unroll
        for (int g = 0; g < 8; ++g) { dot[g] = __expf(dot[g] - m); ssum += dot[g]; }
        const float rinv = 1.f / ssum;
        float o[32];
#pragma unroll
        for (int i = 0; i < 32; ++i) o[i] = 0.f;
#pragma unroll
        for (int g = 0; g < 8; ++g) {
            const float w = dot[g] * rinv;
#pragma unroll
            for (int i = 0; i < 4; ++i) {
                const u16x8 v = *(const u16x8*)&row[512 + g * 32 + i * 8];
#pragma unroll
                for (int e = 0; e < 8; ++e) o[i * 8 + e] += w * bf2f(v[e]);
            }
        }
        // head-OUTER concat == channel layout; store to XO as O[t][c]
#pragma unroll
        for (int i = 0; i < 4; ++i) {
            u16x8 pk;
#pragma unroll
            for (int e = 0; e < 8; ++e) pk[e] = f2bf(o[i * 8 + e]);
            *(u16x8*)&XO[t * LDOe + h * 32 + i * 8] = pk;
        }
    }
    __syncthreads();

    // ---- phase 3: OUT = Wo @ O^T + bo  (M=256, N=32, K=256).
    //      wave owns 32 rows (2 m-tiles) x 2 col-tiles. B-frag reads <=2-way.
    {
        const int l15 = lane & 15;
        const int l4 = lane >> 4;
        const int m_base = wave * 32;
        f32x4 acc[2][2];
#pragma unroll
        for (int i = 0; i < 2; ++i)
#pragma unroll
            for (int j = 0; j < 2; ++j) acc[i][j] = (f32x4){0.f, 0.f, 0.f, 0.f};

#pragma unroll
        for (int kk = 0; kk < 8; ++kk) {
            const int koff = kk * 32 + l4 * 8;
            bf16x8 bfr[2];
#pragma unroll
            for (int ct = 0; ct < 2; ++ct)
                bfr[ct] = __builtin_bit_cast(bf16x8,
                    *(const u16x8*)&XO[(ct * 16 + l15) * LDOe + koff]);
#pragma unroll
            for (int mt = 0; mt < 2; ++mt) {
                const bf16x8 afr = __builtin_bit_cast(bf16x8,
                    *(const u16x8*)&Wo_b[(m_base + mt * 16 + l15) * 256 + koff]);
#pragma unroll
                for (int ct = 0; ct < 2; ++ct)
                    acc[mt][ct] = __builtin_amdgcn_mfma_f32_16x16x32_bf16(
                        afr, bfr[ct], acc[mt][ct], 0, 0, 0);
            }
        }
#pragma unroll
        for (int mt = 0; mt < 2; ++mt) {
            const int c0 = m_base + mt * 16 + l4 * 4;
            const f32x4 bias = *(const f32x4*)&bo[c0];
#pragma unroll
            for (int ct = 0; ct < 2; ++ct) {
                const int hw = hw0 + ct * 16 + l15;
                float* __restrict__ op = out + (((size_t)b * 256 + c0) << 14) + hw;
#pragma unroll
                for (int r = 0; r < 4; ++r)
                    op[(size_t)r << 14] = acc[mt][ct][r] + bias[r];
            }
        }
    }
}

extern "C" void kernel_launch(void* const* d_in, const int* in_sizes, int n_in,
                              void* d_out, int out_size, void* d_ws, size_t ws_size,
                              hipStream_t stream) {
    const float* x_c = (const float*)d_in[0];
    const float* x_t = (const float*)d_in[1];
    const float* Wq = (const float*)d_in[2];
    const float* bq = (const float*)d_in[3];
    const float* Wk = (const float*)d_in[4];
    const float* bk = (const float*)d_in[5];
    const float* Wv = (const float*)d_in[6];
    const float* bv = (const float*)d_in[7];
    const float* Wo = (const float*)d_in[8];
    const float* bo = (const float*)d_in[9];
    float* out = (float*)d_out;
    char* ws = (char*)d_ws;

    u16* Wqkv_b = (u16*)(ws + WS_WQKV);
    u16* Wo_b = (u16*)(ws + WS_WO);
    float* bias_qkv = (float*)(ws + WS_BIAS);

    prep_kernel<<<768, 256, 0, stream>>>(Wq, Wk, Wv, Wo, bq, bk, bv,
                                         Wqkv_b, Wo_b, bias_qkv);
    fused_kernel<<<(8 * HWN) / T, 512, 0, stream>>>(x_c, x_t, Wqkv_b, Wo_b,
                                                    bias_qkv, bo, out);
}